// Round 3
// baseline (1458.448 us; speedup 1.0000x reference)
//
#include <hip/hip_runtime.h>
#include <hip/hip_bf16.h>

#define N_V   50000
#define KTOT  2624        // 41*64
#define NOUT  512         // O*T
#define NKB   41
#define BM    128
#define BN    256
#define KT32  82          // K tiles of 32 for gemm4

typedef short v8s __attribute__((ext_vector_type(8)));
typedef float v4f __attribute__((ext_vector_type(4)));
typedef unsigned int v4u __attribute__((ext_vector_type(4)));
typedef unsigned short u16;
typedef unsigned int u32;

__device__ __forceinline__ u16 f2bf(float f) {
    u32 u = __float_as_uint(f);
    return (u16)((u + 0x7FFFu + ((u >> 16) & 1u)) >> 16);   // RNE
}

__device__ __forceinline__ void gl2lds(const u16* g, u16* l) {
    __builtin_amdgcn_global_load_lds(
        (const __attribute__((address_space(1))) u32*)(uintptr_t)g,
        (__attribute__((address_space(3))) u32*)(uintptr_t)l, 16, 0, 0);
}

__device__ __forceinline__ u32 ipair(u32 pa, u32 pb, u32 pc, float w0, float w1, float w2) {
    float a0 = __uint_as_float(pa << 16), a1 = __uint_as_float(pa & 0xffff0000u);
    float b0 = __uint_as_float(pb << 16), b1 = __uint_as_float(pb & 0xffff0000u);
    float c0 = __uint_as_float(pc << 16), c1 = __uint_as_float(pc & 0xffff0000u);
    float r0 = w0 * a0 + w1 * b0 + w2 * c0;
    float r1 = w0 * a1 + w1 * b1 + w2 * c1;
    return __builtin_amdgcn_perm(__float_as_uint(r1) + 0x8000u,
                                 __float_as_uint(r0) + 0x8000u, 0x07060302u);
}

// ---------- kernel 1: mesh_signal fp32 -> bf16 (+ optional X center columns) ----------
__global__ void cast_ms(const float* __restrict__ ms, u16* __restrict__ msb,
                        u16* __restrict__ Xc) {
    int i = (blockIdx.x * 256 + threadIdx.x) * 4;
    float4 v = *reinterpret_cast<const float4*>(ms + i);
    ushort4 o;
    o.x = f2bf(v.x); o.y = f2bf(v.y); o.z = f2bf(v.z); o.w = f2bf(v.w);
    *reinterpret_cast<ushort4*>(msb + i) = o;
    if (Xc) {
        int n = i >> 6, c = i & 63;
        *reinterpret_cast<ushort4*>(Xc + (size_t)n * KTOT + 2560 + c) = o;
    }
}

// ---------- kernel 2: combined weights (512 x 2624 bf16) ----------
__global__ void build_w2(const float* __restrict__ nw, const float* __restrict__ cw,
                         const float* __restrict__ coeff, u16* __restrict__ w2) {
    int l = blockIdx.x * 256 + threadIdx.x;
    if (l >= NOUT * KTOT) return;
    int j = l / KTOT, k = l - j * KTOT;
    int o = j >> 6, t = j & 63;
    u16 v;
    if (k >= 2560) {
        v = f2bf(cw[t * 64 + (k - 2560)]);
    } else {
        int m = k >> 6, c = k & 63;
        float s = 0.f;
        #pragma unroll
        for (int ra = 0; ra < 40; ++ra) {
            int r = ra >> 3, a = ra & 7;
            s += coeff[ra * 40 + m] * nw[((t * 5 + r) * 8 + ((a + o) & 7)) * 64 + c];
        }
        v = f2bf(s);
    }
    w2[l] = v;
}

// ---------- kernel 3: materialize X (patch operator), dup=1, full occupancy ----------
__global__ void build_x(const float* __restrict__ bary, const u16* __restrict__ msb,
                        u16* __restrict__ X) {
    u32 t = blockIdx.x * 256 + threadIdx.x;       // 8,000,000 exact
    u32 n = t / 160u;
    u32 rem = t - n * 160u;
    u32 m = rem >> 2, j = rem & 3;
    const float* bb = bary + (size_t)n * 240 + m * 6;
    float2 p0 = *(const float2*)(bb);
    float2 p1 = *(const float2*)(bb + 2);
    float2 p2 = *(const float2*)(bb + 4);
    u32 jb = j * 32u;
    u32 o0 = ((u32)(int)p0.x) * 128u + jb;
    u32 o1 = ((u32)(int)p1.x) * 128u + jb;
    u32 o2 = ((u32)(int)p2.x) * 128u + jb;
    const char* mb = (const char*)msb;
    v4u a0 = *(const v4u*)(mb + o0), b0 = *(const v4u*)(mb + o0 + 16);
    v4u a1 = *(const v4u*)(mb + o1), b1 = *(const v4u*)(mb + o1 + 16);
    v4u a2 = *(const v4u*)(mb + o2), b2 = *(const v4u*)(mb + o2 + 16);
    v4u c0, c1;
    #pragma unroll
    for (int e = 0; e < 4; ++e) {
        c0[e] = ipair(a0[e], a1[e], a2[e], p0.y, p1.y, p2.y);
        c1[e] = ipair(b0[e], b1[e], b2[e], p0.y, p1.y, p2.y);
    }
    char* xp = (char*)X + (size_t)n * (KTOT * 2) + m * 128 + jb;
    *(v4u*)xp = c0;
    *(v4u*)(xp + 16) = c1;
}

// ---------- kernel 4: gemm4 — 4 waves, 128x128 wave tiles, dual-resident ----------
// Block 256x256 (256 threads, 2Mx2N waves of 128x128). BK=32, 2-buffer, 64 KiB static LDS
// -> 2 blocks/CU, all 392 blocks resident in ONE round. LDS read demand 0.25 b128/MFMA.
// Per tile: [vmcnt(0); s_barrier] (wait BEFORE barrier = cross-wave LDS visibility),
// then stage t+1 (covered by the full tile ~2500 cyc), then ds_read frags + 64 MFMA.
__global__ __launch_bounds__(256, 2)
void gemm4(const u16* __restrict__ X, const u16* __restrict__ w2,
           const float* __restrict__ bias, float* __restrict__ out) {
    __shared__ u16 sh[32768];   // 64 KiB: A[2][16K] @0, B[2][16K] @32768

    const int tid  = threadIdx.x;
    const int lane = tid & 63, wave = tid >> 6;
    const int l15  = lane & 15, q = lane >> 4;
    const int wm   = wave >> 1, wn = wave & 1;

    // pair-mapping: ids k and k^8 share an XCD (xcd = id % 8) -> X panel L2 reuse
    const int id = blockIdx.x;
    const int p  = (id & 7) + 8 * (id >> 4);
    const int by = (id >> 3) & 1;
    if (p >= 196) return;
    const int row0 = p * 256, col0 = by * 256;

    // staging: 4 A-loads + 4 B-loads per thread per K-tile (16 KB A + 16 KB B).
    // LDS slot (16B units) = i*256 + tid ; row = slot>>2 ; blk = slot&3 ;
    // global source pre-swizzled: g = blk ^ ((row>>1)&3)   (both-sides swizzle rule)
    u32 aoff[4], boff[4];
    #pragma unroll
    for (int i = 0; i < 4; ++i) {
        int s   = i * 256 + tid;
        int row = s >> 2, b = s & 3;
        int g   = b ^ ((row >> 1) & 3);
        int grow = row0 + row; if (grow > N_V - 1) grow = N_V - 1;
        aoff[i] = (u32)grow * (u32)KTOT + (u32)(g * 8);
        boff[i] = (u32)(col0 + row) * (u32)KTOT + (u32)(g * 8);
    }

    // ds_read: row stride 64 B; swizzled 16B-block = q ^ ((row>>1)&3);
    // (row>>1)&3 depends only on l15 bits 1..2 (frag row bases are 16-aligned).
    const int sw = (l15 >> 1) & 3;
    const u32 a_rd0 = (u32)(wm * 128 + l15) * 64u + (u32)((q ^ sw) * 16);
    const u32 b_rd0 = (u32)(wn * 128 + l15) * 64u + (u32)((q ^ sw) * 16);

    v4f acc[8][8];
    #pragma unroll
    for (int mi = 0; mi < 8; ++mi)
        #pragma unroll
        for (int ni = 0; ni < 8; ++ni)
            acc[mi][ni] = (v4f){0.f, 0.f, 0.f, 0.f};

    // gl2lds LDS dest must be WAVE-UNIFORM base (HW appends lane*16).
#define STG4(T, BUF) do { \
    const u32 _ko = (u32)(T) * 32u; \
    _Pragma("unroll") \
    for (int _i = 0; _i < 4; ++_i) { \
        gl2lds(X  + aoff[_i] + _ko, \
               (u16*)((char*)sh + (BUF) * 16384 + _i * 4096 + wave * 1024)); \
        gl2lds(w2 + boff[_i] + _ko, \
               (u16*)((char*)sh + 32768 + (BUF) * 16384 + _i * 4096 + wave * 1024)); \
    } } while (0)

#define CMP4(BUF) do { \
    const char* _ap = (const char*)sh + (BUF) * 16384; \
    const char* _bp = (const char*)sh + 32768 + (BUF) * 16384; \
    v8s _af[8], _bf[8]; \
    _Pragma("unroll") \
    for (int _mi = 0; _mi < 8; ++_mi) _af[_mi] = *(const v8s*)(_ap + a_rd0 + _mi * 1024); \
    _Pragma("unroll") \
    for (int _ni = 0; _ni < 8; ++_ni) _bf[_ni] = *(const v8s*)(_bp + b_rd0 + _ni * 1024); \
    __builtin_amdgcn_s_setprio(1); \
    _Pragma("unroll") \
    for (int _mi = 0; _mi < 8; ++_mi) \
        _Pragma("unroll") \
        for (int _ni = 0; _ni < 8; ++_ni) \
            acc[_mi][_ni] = __builtin_amdgcn_mfma_f32_16x16x32_bf16( \
                _af[_mi], _bf[_ni], acc[_mi][_ni], 0, 0, 0); \
    __builtin_amdgcn_s_setprio(0); \
} while (0)

    STG4(0, 0);
    #pragma unroll 1
    for (int t = 0; t < KT32 - 1; ++t) {
        // vmcnt(0) BEFORE barrier: every wave's tile-t staging retired, then barrier
        // makes it collectively visible; barrier arrival also proves all waves finished
        // reading buf (t+1)&1 at tile t-1 -> safe to overwrite.
        asm volatile("s_waitcnt vmcnt(0)\n\ts_barrier" ::: "memory");
        STG4(t + 1, (t + 1) & 1);
        CMP4(t & 1);
    }
    asm volatile("s_waitcnt vmcnt(0)\n\ts_barrier" ::: "memory");
    CMP4((KT32 - 1) & 1);

#undef STG4
#undef CMP4

    // bias is per-T (64 entries), broadcast over O: index = out_col & 63.
    // cg = col0 + wn*128 + ni*16 + l15 ; col0, wn*128 are multiples of 64 ->
    // cg & 63 = (ni & 3)*16 + l15.   (Round-2 bug: previous code indexed bias OOB.)
    float bv[8];
    #pragma unroll
    for (int ni = 0; ni < 8; ++ni) bv[ni] = bias[(ni & 3) * 16 + l15];
    #pragma unroll
    for (int mi = 0; mi < 8; ++mi) {
        int rbase = row0 + wm * 128 + mi * 16 + q * 4;
        #pragma unroll
        for (int ni = 0; ni < 8; ++ni) {
            int cg = col0 + wn * 128 + ni * 16 + l15;
            #pragma unroll
            for (int rg = 0; rg < 4; ++rg) {
                int rr = rbase + rg;
                if (rr < N_V) {
                    float v = acc[mi][ni][rg] + bv[ni];
                    out[(size_t)rr * NOUT + cg] = v > 0.f ? v : 0.f;
                }
            }
        }
    }
}

// ================= fallback: R3 fused kernel (used only if ws too small) =================
__global__ __launch_bounds__(512, 2)
void gemm_fused(const float* __restrict__ bary, const u16* __restrict__ msb,
                const u16* __restrict__ w2, const float* __restrict__ bias,
                float* __restrict__ out) {
    __shared__ u16 At[BM * 64];
    __shared__ u16 Bt[2 * BN * 64];

    const int tid  = threadIdx.x;
    const int lane = tid & 63, wave = tid >> 6;
    const int l15  = lane & 15, q = lane >> 4;
    const int wm   = wave >> 2, wn = wave & 3;

    const int id  = blockIdx.x;
    const int bx  = id % 391, by = id / 391;
    const int row0 = bx * BM, col0 = by * BN;

    const int ar  = tid >> 2;
    const u32 acb = (u32)(tid & 3) * 32;
    int an = row0 + ar; if (an > N_V - 1) an = N_V - 1;
    const u32* brow = (const u32*)bary + (size_t)an * 240;
    const u32 an_off = (u32)an * 128 + acb;

    const int e_a = ar & 7;
    const u32 at_w0 = (u32)ar * 128 + (u32)(((2 * (tid & 3)) ^ e_a) * 16);
    const u32 at_w1 = at_w0 ^ 16;

    const int eq = l15 & 7;
    const u32 a_rd0 = (u32)(wm * 64 + l15) * 128 + (u32)((q ^ eq) * 16);
    const u32 b_rd0 = (u32)(wn * 64 + l15) * 128 + (u32)((q ^ eq) * 16);

    const int rl = lane >> 3;
    const int bl = (lane & 7) ^ rl;

    v4f acc[4][4];
    #pragma unroll
    for (int mi = 0; mi < 4; ++mi)
        #pragma unroll
        for (int ni = 0; ni < 4; ++ni)
            acc[mi][ni] = (v4f){0.f, 0.f, 0.f, 0.f};

    v4u G0_0a, G0_0b, G0_1a, G0_1b, G0_2a, G0_2b;
    v4u G1_0a, G1_0b, G1_1a, G1_1b, G1_2a, G1_2b;
    v4u B0lo, B0hi, B1lo, B1hi;
    float w00, w01, w02, w10, w11, w12;
    v4u cv0, cv1;

#define BARY_LOAD(DLO, DHI, kc) do { \
    u32 _d0 = ((u32)((kc) * 6)) & ~3u; \
    DLO = *(const v4u*)(brow + _d0); \
    DHI = *(const v4u*)(brow + _d0 + 4); } while (0)

#define DECODE_ISSUE(PAR, BLO, BHI, Ga0, Gb0, Ga1, Gb1, Ga2, Gb2, W0, W1, W2) do { \
    u32 uf0, uw0, uf1, uw1, uf2, uw2; \
    if (PAR) { uf0 = BLO[2]; uw0 = BLO[3]; uf1 = BHI[0]; uw1 = BHI[1]; uf2 = BHI[2]; uw2 = BHI[3]; } \
    else     { uf0 = BLO[0]; uw0 = BLO[1]; uf1 = BLO[2]; uw1 = BLO[3]; uf2 = BHI[0]; uw2 = BHI[1]; } \
    u32 _o0 = ((u32)(int)__uint_as_float(uf0) << 7) + acb; \
    u32 _o1 = ((u32)(int)__uint_as_float(uf1) << 7) + acb; \
    u32 _o2 = ((u32)(int)__uint_as_float(uf2) << 7) + acb; \
    const char* _mb = (const char*)msb; \
    Ga0 = *(const v4u*)(_mb + _o0); Gb0 = *(const v4u*)(_mb + _o0 + 16); \
    Ga1 = *(const v4u*)(_mb + _o1); Gb1 = *(const v4u*)(_mb + _o1 + 16); \
    Ga2 = *(const v4u*)(_mb + _o2); Gb2 = *(const v4u*)(_mb + _o2 + 16); \
    W0 = __uint_as_float(uw0); W1 = __uint_as_float(uw1); W2 = __uint_as_float(uw2); } while (0)

#define CONVERT(Ga0, Gb0, Ga1, Gb1, Ga2, Gb2, W0, W1, W2) do { \
    _Pragma("unroll") \
    for (int _j = 0; _j < 4; ++_j) { \
        cv0[_j] = ipair(Ga0[_j], Ga1[_j], Ga2[_j], W0, W1, W2); \
        cv1[_j] = ipair(Gb0[_j], Gb1[_j], Gb2[_j], W0, W1, W2); } } while (0)

#define BLDS(KB_LD, BUF) do { \
    _Pragma("unroll") \
    for (int _ii = 0; _ii < 4; ++_ii) { \
        int _we = wave * 4 + _ii; \
        u32 _src = (u32)(col0 + _we * 8 + rl) * KTOT + (u32)(KB_LD) * 64 + (u32)(bl * 8); \
        gl2lds(w2 + _src, &Bt[(BUF) * (BN * 64) + _we * 512]); } } while (0)

#define AT_STORE() do { \
    *(v4u*)((char*)At + at_w0) = cv0; \
    *(v4u*)((char*)At + at_w1) = cv1; } while (0)

#define MFMA_STEP(BUF) do { \
    const char* _atp = (const char*)At; \
    const char* _btp = (const char*)Bt + (BUF) * (BN * 64 * 2); \
    _Pragma("unroll") \
    for (int _s = 0; _s < 2; ++_s) { \
        u32 _ao = a_rd0 ^ (u32)(_s * 64), _bo = b_rd0 ^ (u32)(_s * 64); \
        v8s _af[4], _bf[4]; \
        _Pragma("unroll") \
        for (int _mi = 0; _mi < 4; ++_mi) _af[_mi] = *(const v8s*)(_atp + _ao + _mi * 2048); \
        _Pragma("unroll") \
        for (int _ni = 0; _ni < 4; ++_ni) _bf[_ni] = *(const v8s*)(_btp + _bo + _ni * 2048); \
        _Pragma("unroll") \
        for (int _mi = 0; _mi < 4; ++_mi) \
            _Pragma("unroll") \
            for (int _ni = 0; _ni < 4; ++_ni) \
                acc[_mi][_ni] = __builtin_amdgcn_mfma_f32_16x16x32_bf16( \
                    _af[_mi], _bf[_ni], acc[_mi][_ni], 0, 0, 0); } } while (0)

#define BAR2_12() asm volatile("s_waitcnt vmcnt(12) lgkmcnt(0)\ns_barrier" ::: "memory")
#define BAR2_10() asm volatile("s_waitcnt vmcnt(10) lgkmcnt(0)\ns_barrier" ::: "memory")
#define BAR2_6()  asm volatile("s_waitcnt vmcnt(6) lgkmcnt(0)\ns_barrier"  ::: "memory")
#define BAR2_4()  asm volatile("s_waitcnt vmcnt(4) lgkmcnt(0)\ns_barrier"  ::: "memory")
#define BAR2_0()  asm volatile("s_waitcnt vmcnt(0) lgkmcnt(0)\ns_barrier"  ::: "memory")
#define BAR1()    asm volatile("s_barrier" ::: "memory")

    BARY_LOAD(B0lo, B0hi, 0);
    DECODE_ISSUE(0, B0lo, B0hi, G0_0a, G0_0b, G0_1a, G0_1b, G0_2a, G0_2b, w00, w01, w02);
    BARY_LOAD(B1lo, B1hi, 1);
    DECODE_ISSUE(1, B1lo, B1hi, G1_0a, G1_0b, G1_1a, G1_1b, G1_2a, G1_2b, w10, w11, w12);
    BARY_LOAD(B0lo, B0hi, 2);
    BLDS(0, 0);

    #pragma unroll 1
    for (int i = 0; i < 20; ++i) {
        {
            const int kb = 2 * i;
            CONVERT(G0_0a, G0_0b, G0_1a, G0_1b, G0_2a, G0_2b, w00, w01, w02);
            if (kb <= 36) BARY_LOAD(B1lo, B1hi, kb + 3);
            if (kb <= 37) {
                DECODE_ISSUE(0, B0lo, B0hi, G0_0a, G0_0b, G0_1a, G0_1b, G0_2a, G0_2b,
                             w00, w01, w02);
            } else if (kb == 38) {
                G0_0a = *(const v4u*)((const char*)msb + an_off);
                G0_0b = *(const v4u*)((const char*)msb + an_off + 16);
            }
            BAR1();
            BLDS(kb + 1, 1);
            AT_STORE();
            if (kb <= 36) BAR2_12(); else BAR2_6();
            MFMA_STEP(0);
        }
        {
            const int kb = 2 * i + 1;
            CONVERT(G1_0a, G1_0b, G1_1a, G1_1b, G1_2a, G1_2b, w10, w11, w12);
            if (kb <= 36) BARY_LOAD(B0lo, B0hi, kb + 3);
            if (kb <= 37)
                DECODE_ISSUE(1, B1lo, B1hi, G1_0a, G1_0b, G1_1a, G1_1b, G1_2a, G1_2b,
                             w10, w11, w12);
            BAR1();
            BLDS(kb + 1, 0);
            AT_STORE();
            if (kb <= 36) BAR2_12();
            else if (kb == 37) BAR2_10();
            else BAR2_4();
            MFMA_STEP(1);
        }
    }
    {
        cv0 = G0_0a; cv1 = G0_0b;
        BAR1();
        AT_STORE();
        BAR2_0();
        MFMA_STEP(0);
    }

    float bv[4];
    #pragma unroll
    for (int ni = 0; ni < 4; ++ni) bv[ni] = bias[ni * 16 + l15];
    #pragma unroll
    for (int mi = 0; mi < 4; ++mi) {
        int rbase = row0 + wm * 64 + mi * 16 + q * 4;
        #pragma unroll
        for (int ni = 0; ni < 4; ++ni) {
            int cg = col0 + wn * 64 + ni * 16 + l15;
            #pragma unroll
            for (int rg = 0; rg < 4; ++rg) {
                int rr = rbase + rg;
                if (rr < N_V) {
                    float v = acc[mi][ni][rg] + bv[ni];
                    out[(size_t)rr * NOUT + cg] = v > 0.f ? v : 0.f;
                }
            }
        }
    }
}

extern "C" void kernel_launch(void* const* d_in, const int* in_sizes, int n_in,
                              void* d_out, int out_size, void* d_ws, size_t ws_size,
                              hipStream_t stream) {
    const float* ms    = (const float*)d_in[0];
    const float* bary  = (const float*)d_in[1];
    const float* nw    = (const float*)d_in[2];
    const float* cw    = (const float*)d_in[3];
    const float* bias  = (const float*)d_in[4];
    const float* coeff = (const float*)d_in[5];
    float* out = (float*)d_out;

    u16* msb = (u16*)d_ws;                        // 6,400,000 B
    u16* w2  = (u16*)((char*)d_ws + 6400000);     // 2,686,976 B
    const size_t x_off  = 9087104;                // 128-aligned
    const size_t x_need = x_off + (size_t)N_V * KTOT * 2;   // + 262,400,000 B
    u16* X = (u16*)((char*)d_ws + x_off);

    if (ws_size >= x_need) {
        cast_ms<<<3125, 256, 0, stream>>>(ms, msb, X);
        build_w2<<<(NOUT * KTOT + 255) / 256, 256, 0, stream>>>(nw, cw, coeff, w2);
        build_x<<<31250, 256, 0, stream>>>(bary, msb, X);
        gemm4<<<400, 256, 0, stream>>>(X, w2, bias, out);
    } else {
        cast_ms<<<3125, 256, 0, stream>>>(ms, msb, (u16*)nullptr);
        build_w2<<<(NOUT * KTOT + 255) / 256, 256, 0, stream>>>(nw, cw, coeff, w2);
        gemm_fused<<<782, 512, 0, stream>>>(bary, msb, w2, bias, out);
    }
}

// Round 4
// 529.726 us; speedup vs baseline: 2.7532x; 2.7532x over previous
//
#include <hip/hip_runtime.h>
#include <hip/hip_bf16.h>

#define N_V   50000
#define KTOT  2624        // 41*64
#define NOUT  512         // O*T
#define NKB   41
#define BM    128
#define BN    256
#define KT32  82          // K tiles of 32 for gemm4

typedef short v8s __attribute__((ext_vector_type(8)));
typedef float v4f __attribute__((ext_vector_type(4)));
typedef unsigned int v4u __attribute__((ext_vector_type(4)));
typedef unsigned short u16;
typedef unsigned int u32;

__device__ __forceinline__ u16 f2bf(float f) {
    u32 u = __float_as_uint(f);
    return (u16)((u + 0x7FFFu + ((u >> 16) & 1u)) >> 16);   // RNE
}

__device__ __forceinline__ void gl2lds(const u16* g, u16* l) {
    __builtin_amdgcn_global_load_lds(
        (const __attribute__((address_space(1))) u32*)(uintptr_t)g,
        (__attribute__((address_space(3))) u32*)(uintptr_t)l, 16, 0, 0);
}

__device__ __forceinline__ u32 ipair(u32 pa, u32 pb, u32 pc, float w0, float w1, float w2) {
    float a0 = __uint_as_float(pa << 16), a1 = __uint_as_float(pa & 0xffff0000u);
    float b0 = __uint_as_float(pb << 16), b1 = __uint_as_float(pb & 0xffff0000u);
    float c0 = __uint_as_float(pc << 16), c1 = __uint_as_float(pc & 0xffff0000u);
    float r0 = w0 * a0 + w1 * b0 + w2 * c0;
    float r1 = w0 * a1 + w1 * b1 + w2 * c1;
    return __builtin_amdgcn_perm(__float_as_uint(r1) + 0x8000u,
                                 __float_as_uint(r0) + 0x8000u, 0x07060302u);
}

// ---------- kernel 1: mesh_signal fp32 -> bf16 (+ optional X center columns) ----------
__global__ void cast_ms(const float* __restrict__ ms, u16* __restrict__ msb,
                        u16* __restrict__ Xc) {
    int i = (blockIdx.x * 256 + threadIdx.x) * 4;
    float4 v = *reinterpret_cast<const float4*>(ms + i);
    ushort4 o;
    o.x = f2bf(v.x); o.y = f2bf(v.y); o.z = f2bf(v.z); o.w = f2bf(v.w);
    *reinterpret_cast<ushort4*>(msb + i) = o;
    if (Xc) {
        int n = i >> 6, c = i & 63;
        *reinterpret_cast<ushort4*>(Xc + (size_t)n * KTOT + 2560 + c) = o;
    }
}

// ---------- kernel 2: combined weights (512 x 2624 bf16) ----------
__global__ void build_w2(const float* __restrict__ nw, const float* __restrict__ cw,
                         const float* __restrict__ coeff, u16* __restrict__ w2) {
    int l = blockIdx.x * 256 + threadIdx.x;
    if (l >= NOUT * KTOT) return;
    int j = l / KTOT, k = l - j * KTOT;
    int o = j >> 6, t = j & 63;
    u16 v;
    if (k >= 2560) {
        v = f2bf(cw[t * 64 + (k - 2560)]);
    } else {
        int m = k >> 6, c = k & 63;
        float s = 0.f;
        #pragma unroll
        for (int ra = 0; ra < 40; ++ra) {
            int r = ra >> 3, a = ra & 7;
            s += coeff[ra * 40 + m] * nw[((t * 5 + r) * 8 + ((a + o) & 7)) * 64 + c];
        }
        v = f2bf(s);
    }
    w2[l] = v;
}

// ---------- kernel 3: materialize X (patch operator), dup=1, full occupancy ----------
__global__ void build_x(const float* __restrict__ bary, const u16* __restrict__ msb,
                        u16* __restrict__ X) {
    u32 t = blockIdx.x * 256 + threadIdx.x;       // 8,000,000 exact
    u32 n = t / 160u;
    u32 rem = t - n * 160u;
    u32 m = rem >> 2, j = rem & 3;
    const float* bb = bary + (size_t)n * 240 + m * 6;
    float2 p0 = *(const float2*)(bb);
    float2 p1 = *(const float2*)(bb + 2);
    float2 p2 = *(const float2*)(bb + 4);
    u32 jb = j * 32u;
    u32 o0 = ((u32)(int)p0.x) * 128u + jb;
    u32 o1 = ((u32)(int)p1.x) * 128u + jb;
    u32 o2 = ((u32)(int)p2.x) * 128u + jb;
    const char* mb = (const char*)msb;
    v4u a0 = *(const v4u*)(mb + o0), b0 = *(const v4u*)(mb + o0 + 16);
    v4u a1 = *(const v4u*)(mb + o1), b1 = *(const v4u*)(mb + o1 + 16);
    v4u a2 = *(const v4u*)(mb + o2), b2 = *(const v4u*)(mb + o2 + 16);
    v4u c0, c1;
    #pragma unroll
    for (int e = 0; e < 4; ++e) {
        c0[e] = ipair(a0[e], a1[e], a2[e], p0.y, p1.y, p2.y);
        c1[e] = ipair(b0[e], b1[e], b2[e], p0.y, p1.y, p2.y);
    }
    char* xp = (char*)X + (size_t)n * (KTOT * 2) + m * 128 + jb;
    *(v4u*)xp = c0;
    *(v4u*)(xp + 16) = c1;
}

// ---------- kernel 4: gemm4 — 4 waves, 128x128 wave tiles ----------
// Block 256x256 (256 threads, 2Mx2N waves of 128x128). BK=32, 2-buffer, 64 KiB LDS.
// __launch_bounds__(256, 1): the accumulator alone is 256 VGPRs; with min-2-waves/EU
// the allocator was capped at 128 and spilled acc to scratch (round 3: 3.9 GB HBM
// traffic, MfmaUtil 4.5%). At 1 wave/SIMD the full 512-reg file is available
// (~350 needed) -> no spill; 32 independent acc tiles give the MFMA ILP.
// Per tile: [vmcnt(0); s_barrier] (wait BEFORE barrier = cross-wave LDS visibility),
// then stage t+1 (covered by the ~1024-cyc MFMA block), then ds_read frags + 64 MFMA.
__global__ __launch_bounds__(256, 1)
void gemm4(const u16* __restrict__ X, const u16* __restrict__ w2,
           const float* __restrict__ bias, float* __restrict__ out) {
    __shared__ u16 sh[32768];   // 64 KiB: A[2][16K] @0, B[2][16K] @32768

    const int tid  = threadIdx.x;
    const int lane = tid & 63, wave = tid >> 6;
    const int l15  = lane & 15, q = lane >> 4;
    const int wm   = wave >> 1, wn = wave & 1;

    // pair-mapping: ids k and k^8 share an XCD (xcd = id % 8) -> X panel L2 reuse
    const int id = blockIdx.x;
    const int p  = (id & 7) + 8 * (id >> 4);
    const int by = (id >> 3) & 1;
    if (p >= 196) return;
    const int row0 = p * 256, col0 = by * 256;

    // staging: 4 A-loads + 4 B-loads per thread per K-tile (16 KB A + 16 KB B).
    // LDS slot (16B units) = i*256 + tid ; row = slot>>2 ; blk = slot&3 ;
    // global source pre-swizzled: g = blk ^ ((row>>1)&3)   (both-sides swizzle rule)
    u32 aoff[4], boff[4];
    #pragma unroll
    for (int i = 0; i < 4; ++i) {
        int s   = i * 256 + tid;
        int row = s >> 2, b = s & 3;
        int g   = b ^ ((row >> 1) & 3);
        int grow = row0 + row; if (grow > N_V - 1) grow = N_V - 1;
        aoff[i] = (u32)grow * (u32)KTOT + (u32)(g * 8);
        boff[i] = (u32)(col0 + row) * (u32)KTOT + (u32)(g * 8);
    }

    // ds_read: row stride 64 B; swizzled 16B-block = q ^ ((row>>1)&3);
    // (row>>1)&3 depends only on l15 bits 1..2 (frag row bases are 16-aligned).
    const int sw = (l15 >> 1) & 3;
    const u32 a_rd0 = (u32)(wm * 128 + l15) * 64u + (u32)((q ^ sw) * 16);
    const u32 b_rd0 = (u32)(wn * 128 + l15) * 64u + (u32)((q ^ sw) * 16);

    v4f acc[8][8];
    #pragma unroll
    for (int mi = 0; mi < 8; ++mi)
        #pragma unroll
        for (int ni = 0; ni < 8; ++ni)
            acc[mi][ni] = (v4f){0.f, 0.f, 0.f, 0.f};

    // gl2lds LDS dest must be WAVE-UNIFORM base (HW appends lane*16).
#define STG4(T, BUF) do { \
    const u32 _ko = (u32)(T) * 32u; \
    _Pragma("unroll") \
    for (int _i = 0; _i < 4; ++_i) { \
        gl2lds(X  + aoff[_i] + _ko, \
               (u16*)((char*)sh + (BUF) * 16384 + _i * 4096 + wave * 1024)); \
        gl2lds(w2 + boff[_i] + _ko, \
               (u16*)((char*)sh + 32768 + (BUF) * 16384 + _i * 4096 + wave * 1024)); \
    } } while (0)

#define CMP4(BUF) do { \
    const char* _ap = (const char*)sh + (BUF) * 16384; \
    const char* _bp = (const char*)sh + 32768 + (BUF) * 16384; \
    v8s _af[8], _bf[8]; \
    _Pragma("unroll") \
    for (int _mi = 0; _mi < 8; ++_mi) _af[_mi] = *(const v8s*)(_ap + a_rd0 + _mi * 1024); \
    _Pragma("unroll") \
    for (int _ni = 0; _ni < 8; ++_ni) _bf[_ni] = *(const v8s*)(_bp + b_rd0 + _ni * 1024); \
    __builtin_amdgcn_s_setprio(1); \
    _Pragma("unroll") \
    for (int _mi = 0; _mi < 8; ++_mi) \
        _Pragma("unroll") \
        for (int _ni = 0; _ni < 8; ++_ni) \
            acc[_mi][_ni] = __builtin_amdgcn_mfma_f32_16x16x32_bf16( \
                _af[_mi], _bf[_ni], acc[_mi][_ni], 0, 0, 0); \
    __builtin_amdgcn_s_setprio(0); \
} while (0)

    STG4(0, 0);
    #pragma unroll 1
    for (int t = 0; t < KT32 - 1; ++t) {
        // vmcnt(0) BEFORE barrier: every wave's tile-t staging retired, then barrier
        // makes it collectively visible; barrier arrival also proves all waves finished
        // reading buf (t+1)&1 at tile t-1 -> safe to overwrite.
        asm volatile("s_waitcnt vmcnt(0)\n\ts_barrier" ::: "memory");
        STG4(t + 1, (t + 1) & 1);
        CMP4(t & 1);
    }
    asm volatile("s_waitcnt vmcnt(0)\n\ts_barrier" ::: "memory");
    CMP4((KT32 - 1) & 1);

#undef STG4
#undef CMP4

    // bias is per-T (64 entries), broadcast over O: index = out_col & 63.
    // cg = col0 + wn*128 + ni*16 + l15 ; col0, wn*128 are multiples of 64 ->
    // cg & 63 = (ni & 3)*16 + l15.
    float bv[8];
    #pragma unroll
    for (int ni = 0; ni < 8; ++ni) bv[ni] = bias[(ni & 3) * 16 + l15];
    #pragma unroll
    for (int mi = 0; mi < 8; ++mi) {
        int rbase = row0 + wm * 128 + mi * 16 + q * 4;
        #pragma unroll
        for (int ni = 0; ni < 8; ++ni) {
            int cg = col0 + wn * 128 + ni * 16 + l15;
            #pragma unroll
            for (int rg = 0; rg < 4; ++rg) {
                int rr = rbase + rg;
                if (rr < N_V) {
                    float v = acc[mi][ni][rg] + bv[ni];
                    out[(size_t)rr * NOUT + cg] = v > 0.f ? v : 0.f;
                }
            }
        }
    }
}

// ================= fallback: R3 fused kernel (used only if ws too small) =================
__global__ __launch_bounds__(512, 2)
void gemm_fused(const float* __restrict__ bary, const u16* __restrict__ msb,
                const u16* __restrict__ w2, const float* __restrict__ bias,
                float* __restrict__ out) {
    __shared__ u16 At[BM * 64];
    __shared__ u16 Bt[2 * BN * 64];

    const int tid  = threadIdx.x;
    const int lane = tid & 63, wave = tid >> 6;
    const int l15  = lane & 15, q = lane >> 4;
    const int wm   = wave >> 2, wn = wave & 3;

    const int id  = blockIdx.x;
    const int bx  = id % 391, by = id / 391;
    const int row0 = bx * BM, col0 = by * BN;

    const int ar  = tid >> 2;
    const u32 acb = (u32)(tid & 3) * 32;
    int an = row0 + ar; if (an > N_V - 1) an = N_V - 1;
    const u32* brow = (const u32*)bary + (size_t)an * 240;
    const u32 an_off = (u32)an * 128 + acb;

    const int e_a = ar & 7;
    const u32 at_w0 = (u32)ar * 128 + (u32)(((2 * (tid & 3)) ^ e_a) * 16);
    const u32 at_w1 = at_w0 ^ 16;

    const int eq = l15 & 7;
    const u32 a_rd0 = (u32)(wm * 64 + l15) * 128 + (u32)((q ^ eq) * 16);
    const u32 b_rd0 = (u32)(wn * 64 + l15) * 128 + (u32)((q ^ eq) * 16);

    const int rl = lane >> 3;
    const int bl = (lane & 7) ^ rl;

    v4f acc[4][4];
    #pragma unroll
    for (int mi = 0; mi < 4; ++mi)
        #pragma unroll
        for (int ni = 0; ni < 4; ++ni)
            acc[mi][ni] = (v4f){0.f, 0.f, 0.f, 0.f};

    v4u G0_0a, G0_0b, G0_1a, G0_1b, G0_2a, G0_2b;
    v4u G1_0a, G1_0b, G1_1a, G1_1b, G1_2a, G1_2b;
    v4u B0lo, B0hi, B1lo, B1hi;
    float w00, w01, w02, w10, w11, w12;
    v4u cv0, cv1;

#define BARY_LOAD(DLO, DHI, kc) do { \
    u32 _d0 = ((u32)((kc) * 6)) & ~3u; \
    DLO = *(const v4u*)(brow + _d0); \
    DHI = *(const v4u*)(brow + _d0 + 4); } while (0)

#define DECODE_ISSUE(PAR, BLO, BHI, Ga0, Gb0, Ga1, Gb1, Ga2, Gb2, W0, W1, W2) do { \
    u32 uf0, uw0, uf1, uw1, uf2, uw2; \
    if (PAR) { uf0 = BLO[2]; uw0 = BLO[3]; uf1 = BHI[0]; uw1 = BHI[1]; uf2 = BHI[2]; uw2 = BHI[3]; } \
    else     { uf0 = BLO[0]; uw0 = BLO[1]; uf1 = BLO[2]; uw1 = BLO[3]; uf2 = BHI[0]; uw2 = BHI[1]; } \
    u32 _o0 = ((u32)(int)__uint_as_float(uf0) << 7) + acb; \
    u32 _o1 = ((u32)(int)__uint_as_float(uf1) << 7) + acb; \
    u32 _o2 = ((u32)(int)__uint_as_float(uf2) << 7) + acb; \
    const char* _mb = (const char*)msb; \
    Ga0 = *(const v4u*)(_mb + _o0); Gb0 = *(const v4u*)(_mb + _o0 + 16); \
    Ga1 = *(const v4u*)(_mb + _o1); Gb1 = *(const v4u*)(_mb + _o1 + 16); \
    Ga2 = *(const v4u*)(_mb + _o2); Gb2 = *(const v4u*)(_mb + _o2 + 16); \
    W0 = __uint_as_float(uw0); W1 = __uint_as_float(uw1); W2 = __uint_as_float(uw2); } while (0)

#define CONVERT(Ga0, Gb0, Ga1, Gb1, Ga2, Gb2, W0, W1, W2) do { \
    _Pragma("unroll") \
    for (int _j = 0; _j < 4; ++_j) { \
        cv0[_j] = ipair(Ga0[_j], Ga1[_j], Ga2[_j], W0, W1, W2); \
        cv1[_j] = ipair(Gb0[_j], Gb1[_j], Gb2[_j], W0, W1, W2); } } while (0)

#define BLDS(KB_LD, BUF) do { \
    _Pragma("unroll") \
    for (int _ii = 0; _ii < 4; ++_ii) { \
        int _we = wave * 4 + _ii; \
        u32 _src = (u32)(col0 + _we * 8 + rl) * KTOT + (u32)(KB_LD) * 64 + (u32)(bl * 8); \
        gl2lds(w2 + _src, &Bt[(BUF) * (BN * 64) + _we * 512]); } } while (0)

#define AT_STORE() do { \
    *(v4u*)((char*)At + at_w0) = cv0; \
    *(v4u*)((char*)At + at_w1) = cv1; } while (0)

#define MFMA_STEP(BUF) do { \
    const char* _atp = (const char*)At; \
    const char* _btp = (const char*)Bt + (BUF) * (BN * 64 * 2); \
    _Pragma("unroll") \
    for (int _s = 0; _s < 2; ++_s) { \
        u32 _ao = a_rd0 ^ (u32)(_s * 64), _bo = b_rd0 ^ (u32)(_s * 64); \
        v8s _af[4], _bf[4]; \
        _Pragma("unroll") \
        for (int _mi = 0; _mi < 4; ++_mi) _af[_mi] = *(const v8s*)(_atp + _ao + _mi * 2048); \
        _Pragma("unroll") \
        for (int _ni = 0; _ni < 4; ++_ni) _bf[_ni] = *(const v8s*)(_btp + _bo + _ni * 2048); \
        _Pragma("unroll") \
        for (int _mi = 0; _mi < 4; ++_mi) \
            _Pragma("unroll") \
            for (int _ni = 0; _ni < 4; ++_ni) \
                acc[_mi][_ni] = __builtin_amdgcn_mfma_f32_16x16x32_bf16( \
                    _af[_mi], _bf[_ni], acc[_mi][_ni], 0, 0, 0); } } while (0)

#define BAR2_12() asm volatile("s_waitcnt vmcnt(12) lgkmcnt(0)\ns_barrier" ::: "memory")
#define BAR2_10() asm volatile("s_waitcnt vmcnt(10) lgkmcnt(0)\ns_barrier" ::: "memory")
#define BAR2_6()  asm volatile("s_waitcnt vmcnt(6) lgkmcnt(0)\ns_barrier"  ::: "memory")
#define BAR2_4()  asm volatile("s_waitcnt vmcnt(4) lgkmcnt(0)\ns_barrier"  ::: "memory")
#define BAR2_0()  asm volatile("s_waitcnt vmcnt(0) lgkmcnt(0)\ns_barrier"  ::: "memory")
#define BAR1()    asm volatile("s_barrier" ::: "memory")

    BARY_LOAD(B0lo, B0hi, 0);
    DECODE_ISSUE(0, B0lo, B0hi, G0_0a, G0_0b, G0_1a, G0_1b, G0_2a, G0_2b, w00, w01, w02);
    BARY_LOAD(B1lo, B1hi, 1);
    DECODE_ISSUE(1, B1lo, B1hi, G1_0a, G1_0b, G1_1a, G1_1b, G1_2a, G1_2b, w10, w11, w12);
    BARY_LOAD(B0lo, B0hi, 2);
    BLDS(0, 0);

    #pragma unroll 1
    for (int i = 0; i < 20; ++i) {
        {
            const int kb = 2 * i;
            CONVERT(G0_0a, G0_0b, G0_1a, G0_1b, G0_2a, G0_2b, w00, w01, w02);
            if (kb <= 36) BARY_LOAD(B1lo, B1hi, kb + 3);
            if (kb <= 37) {
                DECODE_ISSUE(0, B0lo, B0hi, G0_0a, G0_0b, G0_1a, G0_1b, G0_2a, G0_2b,
                             w00, w01, w02);
            } else if (kb == 38) {
                G0_0a = *(const v4u*)((const char*)msb + an_off);
                G0_0b = *(const v4u*)((const char*)msb + an_off + 16);
            }
            BAR1();
            BLDS(kb + 1, 1);
            AT_STORE();
            if (kb <= 36) BAR2_12(); else BAR2_6();
            MFMA_STEP(0);
        }
        {
            const int kb = 2 * i + 1;
            CONVERT(G1_0a, G1_0b, G1_1a, G1_1b, G1_2a, G1_2b, w10, w11, w12);
            if (kb <= 36) BARY_LOAD(B0lo, B0hi, kb + 3);
            if (kb <= 37)
                DECODE_ISSUE(1, B1lo, B1hi, G1_0a, G1_0b, G1_1a, G1_1b, G1_2a, G1_2b,
                             w10, w11, w12);
            BAR1();
            BLDS(kb + 1, 0);
            AT_STORE();
            if (kb <= 36) BAR2_12();
            else if (kb == 37) BAR2_10();
            else BAR2_4();
            MFMA_STEP(1);
        }
    }
    {
        cv0 = G0_0a; cv1 = G0_0b;
        BAR1();
        AT_STORE();
        BAR2_0();
        MFMA_STEP(0);
    }

    float bv[4];
    #pragma unroll
    for (int ni = 0; ni < 4; ++ni) bv[ni] = bias[ni * 16 + l15];
    #pragma unroll
    for (int mi = 0; mi < 4; ++mi) {
        int rbase = row0 + wm * 64 + mi * 16 + q * 4;
        #pragma unroll
        for (int ni = 0; ni < 4; ++ni) {
            int cg = col0 + wn * 64 + ni * 16 + l15;
            #pragma unroll
            for (int rg = 0; rg < 4; ++rg) {
                int rr = rbase + rg;
                if (rr < N_V) {
                    float v = acc[mi][ni][rg] + bv[ni];
                    out[(size_t)rr * NOUT + cg] = v > 0.f ? v : 0.f;
                }
            }
        }
    }
}

extern "C" void kernel_launch(void* const* d_in, const int* in_sizes, int n_in,
                              void* d_out, int out_size, void* d_ws, size_t ws_size,
                              hipStream_t stream) {
    const float* ms    = (const float*)d_in[0];
    const float* bary  = (const float*)d_in[1];
    const float* nw    = (const float*)d_in[2];
    const float* cw    = (const float*)d_in[3];
    const float* bias  = (const float*)d_in[4];
    const float* coeff = (const float*)d_in[5];
    float* out = (float*)d_out;

    u16* msb = (u16*)d_ws;                        // 6,400,000 B
    u16* w2  = (u16*)((char*)d_ws + 6400000);     // 2,686,976 B
    const size_t x_off  = 9087104;                // 128-aligned
    const size_t x_need = x_off + (size_t)N_V * KTOT * 2;   // + 262,400,000 B
    u16* X = (u16*)((char*)d_ws + x_off);

    if (ws_size >= x_need) {
        cast_ms<<<3125, 256, 0, stream>>>(ms, msb, X);
        build_w2<<<(NOUT * KTOT + 255) / 256, 256, 0, stream>>>(nw, cw, coeff, w2);
        build_x<<<31250, 256, 0, stream>>>(bary, msb, X);
        gemm4<<<400, 256, 0, stream>>>(X, w2, bias, out);
    } else {
        cast_ms<<<3125, 256, 0, stream>>>(ms, msb, (u16*)nullptr);
        build_w2<<<(NOUT * KTOT + 255) / 256, 256, 0, stream>>>(nw, cw, coeff, w2);
        gemm_fused<<<782, 512, 0, stream>>>(bary, msb, w2, bias, out);
    }
}

// Round 6
// 455.032 us; speedup vs baseline: 3.2052x; 1.1641x over previous
//
#include <hip/hip_runtime.h>
#include <hip/hip_bf16.h>

#define N_V   50000
#define KTOT  2624        // 41*64
#define NOUT  512         // O*T
#define NKB   41
#define BM    128
#define BN    256
#define NT32  82          // K tiles of 32 for gemm5

typedef short v8s __attribute__((ext_vector_type(8)));
typedef float v4f __attribute__((ext_vector_type(4)));
typedef unsigned int v4u __attribute__((ext_vector_type(4)));
typedef unsigned short u16;
typedef unsigned int u32;

__device__ __forceinline__ u16 f2bf(float f) {
    u32 u = __float_as_uint(f);
    return (u16)((u + 0x7FFFu + ((u >> 16) & 1u)) >> 16);   // RNE
}

__device__ __forceinline__ void gl2lds(const u16* g, u16* l) {
    __builtin_amdgcn_global_load_lds(
        (const __attribute__((address_space(1))) u32*)(uintptr_t)g,
        (__attribute__((address_space(3))) u32*)(uintptr_t)l, 16, 0, 0);
}

__device__ __forceinline__ u32 ipair(u32 pa, u32 pb, u32 pc, float w0, float w1, float w2) {
    float a0 = __uint_as_float(pa << 16), a1 = __uint_as_float(pa & 0xffff0000u);
    float b0 = __uint_as_float(pb << 16), b1 = __uint_as_float(pb & 0xffff0000u);
    float c0 = __uint_as_float(pc << 16), c1 = __uint_as_float(pc & 0xffff0000u);
    float r0 = w0 * a0 + w1 * b0 + w2 * c0;
    float r1 = w0 * a1 + w1 * b1 + w2 * c1;
    return __builtin_amdgcn_perm(__float_as_uint(r1) + 0x8000u,
                                 __float_as_uint(r0) + 0x8000u, 0x07060302u);
}

// ---------- kernel 1: mesh_signal fp32 -> bf16 (+ optional X center columns) ----------
__global__ void cast_ms(const float* __restrict__ ms, u16* __restrict__ msb,
                        u16* __restrict__ Xc) {
    int i = (blockIdx.x * 256 + threadIdx.x) * 4;
    float4 v = *reinterpret_cast<const float4*>(ms + i);
    ushort4 o;
    o.x = f2bf(v.x); o.y = f2bf(v.y); o.z = f2bf(v.z); o.w = f2bf(v.w);
    *reinterpret_cast<ushort4*>(msb + i) = o;
    if (Xc) {
        int n = i >> 6, c = i & 63;
        *reinterpret_cast<ushort4*>(Xc + (size_t)n * KTOT + 2560 + c) = o;
    }
}

// ---------- kernel 2: combined weights (512 x 2624 bf16) ----------
__global__ void build_w2(const float* __restrict__ nw, const float* __restrict__ cw,
                         const float* __restrict__ coeff, u16* __restrict__ w2) {
    int l = blockIdx.x * 256 + threadIdx.x;
    if (l >= NOUT * KTOT) return;
    int j = l / KTOT, k = l - j * KTOT;
    int o = j >> 6, t = j & 63;
    u16 v;
    if (k >= 2560) {
        v = f2bf(cw[t * 64 + (k - 2560)]);
    } else {
        int m = k >> 6, c = k & 63;
        float s = 0.f;
        #pragma unroll
        for (int ra = 0; ra < 40; ++ra) {
            int r = ra >> 3, a = ra & 7;
            s += coeff[ra * 40 + m] * nw[((t * 5 + r) * 8 + ((a + o) & 7)) * 64 + c];
        }
        v = f2bf(s);
    }
    w2[l] = v;
}

// ---------- kernel 3: materialize X (patch operator), dup=1, full occupancy ----------
__global__ void build_x(const float* __restrict__ bary, const u16* __restrict__ msb,
                        u16* __restrict__ X) {
    u32 t = blockIdx.x * 256 + threadIdx.x;       // 8,000,000 exact
    u32 n = t / 160u;
    u32 rem = t - n * 160u;
    u32 m = rem >> 2, j = rem & 3;
    const float* bb = bary + (size_t)n * 240 + m * 6;
    float2 p0 = *(const float2*)(bb);
    float2 p1 = *(const float2*)(bb + 2);
    float2 p2 = *(const float2*)(bb + 4);
    u32 jb = j * 32u;
    u32 o0 = ((u32)(int)p0.x) * 128u + jb;
    u32 o1 = ((u32)(int)p1.x) * 128u + jb;
    u32 o2 = ((u32)(int)p2.x) * 128u + jb;
    const char* mb = (const char*)msb;
    v4u a0 = *(const v4u*)(mb + o0), b0 = *(const v4u*)(mb + o0 + 16);
    v4u a1 = *(const v4u*)(mb + o1), b1 = *(const v4u*)(mb + o1 + 16);
    v4u a2 = *(const v4u*)(mb + o2), b2 = *(const v4u*)(mb + o2 + 16);
    v4u c0, c1;
    #pragma unroll
    for (int e = 0; e < 4; ++e) {
        c0[e] = ipair(a0[e], a1[e], a2[e], p0.y, p1.y, p2.y);
        c1[e] = ipair(b0[e], b1[e], b2[e], p0.y, p1.y, p2.y);
    }
    char* xp = (char*)X + (size_t)n * (KTOT * 2) + m * 128 + jb;
    *(v4u*)xp = c0;
    *(v4u*)(xp + 16) = c1;
}

// ---------- kernel 4: gemm5 — 256x256 block, 8 waves (2Mx4N), wave-tile 128x64 ----------
// BK=32 (82 tiles), 3-buffer LDS ring (96 KiB dynamic), distance-2 prefetch.
// acc[8][4] = 128 AGPR + ~60 VGPR -> <=256/wave -> 8 waves/CU (2/SIMD).
// Per tile, 2 phases: {stage chunk0 of t+2 -> vmcnt(6)+barrier -> PH0 (B frags +
// A rows 0..63/128..191, 16 MFMA) -> barrier -> stage chunk1 of t+2 -> PH1 -> barrier}.
// vmcnt never 0 in the main loop (T4). Ledger: entering tile t, 8 loads in flight
// (t c0,c1 + t+1 c0,c1 ... precisely: t's 4 + t+1's 4); +2 at issue -> wait oldest 4
// (= both chunks of tile t) -> vmcnt(6). Peeled t=80 (WB4), t=81 (WB0).
// Ring safety: stage into (t+2)%3 = (t-1)%3 issues after end-barrier of t-1, whose
// readers' ds_reads completed (MFMA data dep) before arrival -> no overwrite race.
// ROUND-5 BUG FIX: b2 was "(bt+2==3)?0:bt+2" -> 4 for bt==2 (OOB LDS write + stale
// buf1 reads, absmax 12.3). Correct: b2 = (bt+2)%3 = bt ? bt-1 : 2.
#define WB6() asm volatile("s_waitcnt vmcnt(6)\n\ts_barrier" ::: "memory")
#define WB4() asm volatile("s_waitcnt vmcnt(4)\n\ts_barrier" ::: "memory")
#define WB0() asm volatile("s_waitcnt vmcnt(0)\n\ts_barrier" ::: "memory")
#define BARO() asm volatile("s_barrier" ::: "memory")

__global__ __launch_bounds__(512, 2)
void gemm5(const u16* __restrict__ X, const u16* __restrict__ w2,
           const float* __restrict__ bias, float* __restrict__ out) {
    extern __shared__ char lds[];   // 3 bufs x (A 16K + B 16K) = 96 KiB

    const int tid  = threadIdx.x;
    const int lane = tid & 63, wave = tid >> 6;
    const int l15  = lane & 15, q = lane >> 4;
    const int wm   = wave >> 2, wn = wave & 3;      // 2M x 4N

    // pair-mapping: ids k and k^8 share an XCD (xcd = id % 8) -> X panel L2 reuse
    const int id = blockIdx.x;
    const int p  = (id & 7) + 8 * (id >> 4);
    const int by = (id >> 3) & 1;
    if (p >= 196) return;
    const int row0 = p * 256, col0 = by * 256;

    // staging: 2 A + 2 B loads per thread per K-tile (16 KB A + 16 KB B).
    // slot s = i*512 + tid (16B units); row = s>>2; blk = s&3;
    // global source pre-swizzled g = blk ^ ((row>>1)&3)  (both-sides rule; verified gemm4)
    u32 aoff[2], boff[2];
    #pragma unroll
    for (int i = 0; i < 2; ++i) {
        int s   = i * 512 + tid;
        int row = s >> 2, b = s & 3;
        int g   = b ^ ((row >> 1) & 3);
        int grow = row0 + row; if (grow > N_V - 1) grow = N_V - 1;
        aoff[i] = (u32)grow * (u32)KTOT + (u32)(g * 8);
        boff[i] = (u32)(col0 + row) * (u32)KTOT + (u32)(g * 8);
    }

    // ds_read: row stride 64 B; swizzled 16B-block = q ^ ((row>>1)&3)
    // ((row>>1)&3 depends only on l15 bits 1..2; frag bases are 16-row aligned).
    const int sw = (l15 >> 1) & 3;
    const u32 a_rd0 = (u32)(wm * 128 + l15) * 64u + (u32)((q ^ sw) * 16);
    const u32 b_rd0 = (u32)(wn * 64  + l15) * 64u + (u32)((q ^ sw) * 16);

    v4f acc[8][4];
    #pragma unroll
    for (int mi = 0; mi < 8; ++mi)
        #pragma unroll
        for (int ni = 0; ni < 4; ++ni)
            acc[mi][ni] = (v4f){0.f, 0.f, 0.f, 0.f};

    // gl2lds LDS dest is wave-uniform base (HW appends lane*16).
#define STG_P(T, BUF, PH) do { \
    gl2lds(X  + aoff[PH] + (u32)(T) * 32u, \
           (u16*)(lds + (BUF) * 32768 + (PH) * 8192 + wave * 1024)); \
    gl2lds(w2 + boff[PH] + (u32)(T) * 32u, \
           (u16*)(lds + (BUF) * 32768 + 16384 + (PH) * 8192 + wave * 1024)); \
} while (0)

#define PH0(BUF) do { \
    const char* _ap = lds + (BUF) * 32768; \
    const char* _bp = _ap + 16384; \
    _Pragma("unroll") \
    for (int _ni = 0; _ni < 4; ++_ni) bf[_ni] = *(const v8s*)(_bp + b_rd0 + _ni * 1024); \
    _Pragma("unroll") \
    for (int _mi = 0; _mi < 4; ++_mi) af[_mi] = *(const v8s*)(_ap + a_rd0 + _mi * 1024); \
    __builtin_amdgcn_s_setprio(1); \
    _Pragma("unroll") \
    for (int _mi = 0; _mi < 4; ++_mi) \
        _Pragma("unroll") \
        for (int _ni = 0; _ni < 4; ++_ni) \
            acc[_mi][_ni] = __builtin_amdgcn_mfma_f32_16x16x32_bf16( \
                af[_mi], bf[_ni], acc[_mi][_ni], 0, 0, 0); \
    __builtin_amdgcn_s_setprio(0); \
} while (0)

#define PH1(BUF) do { \
    const char* _ap = lds + (BUF) * 32768; \
    _Pragma("unroll") \
    for (int _mi = 0; _mi < 4; ++_mi) af[_mi] = *(const v8s*)(_ap + a_rd0 + (4 + _mi) * 1024); \
    __builtin_amdgcn_s_setprio(1); \
    _Pragma("unroll") \
    for (int _mi = 0; _mi < 4; ++_mi) \
        _Pragma("unroll") \
        for (int _ni = 0; _ni < 4; ++_ni) \
            acc[4 + _mi][_ni] = __builtin_amdgcn_mfma_f32_16x16x32_bf16( \
                af[_mi], bf[_ni], acc[4 + _mi][_ni], 0, 0, 0); \
    __builtin_amdgcn_s_setprio(0); \
} while (0)

    v8s af[4], bf[4];

    // prologue: tiles 0 -> buf0, 1 -> buf1  (8 loads in flight)
    STG_P(0, 0, 0); STG_P(0, 0, 1);
    STG_P(1, 1, 0); STG_P(1, 1, 1);

    int bt = 0;                      // buf of tile t (= t % 3)
    #pragma unroll 1
    for (int t = 0; t < NT32 - 2; ++t) {
        const int b2 = bt ? bt - 1 : 2;     // (t+2)%3 == (bt+2)%3  [round-5 fix]
        STG_P(t + 2, b2, 0);         // issue-early: chunk 0 of tile t+2
        WB6();                       // tile t's 4 loads done; 6 younger stay in flight
        PH0(bt);
        BARO();
        STG_P(t + 2, b2, 1);         // chunk 1 of tile t+2
        PH1(bt);
        BARO();
        bt = (bt == 2) ? 0 : bt + 1;
    }
    // t = 80 (buf 2): outstanding = tile 80's 4 + tile 81's 4; wait tile 80
    WB4(); PH0(bt); BARO(); PH1(bt); BARO();
    bt = (bt == 2) ? 0 : bt + 1;
    // t = 81 (buf 0): drain
    WB0(); PH0(bt); BARO(); PH1(bt);

#undef STG_P
#undef PH0
#undef PH1

    // bias is per-T (64 entries): cg & 63 = ni*16 + l15 (wn*64, col0 are mult. of 64)
    float bv[4];
    #pragma unroll
    for (int ni = 0; ni < 4; ++ni) bv[ni] = bias[ni * 16 + l15];
    #pragma unroll
    for (int mi = 0; mi < 8; ++mi) {
        int rbase = row0 + wm * 128 + mi * 16 + q * 4;
        #pragma unroll
        for (int ni = 0; ni < 4; ++ni) {
            int cg = col0 + wn * 64 + ni * 16 + l15;
            #pragma unroll
            for (int rg = 0; rg < 4; ++rg) {
                int rr = rbase + rg;
                if (rr < N_V) {
                    float v = acc[mi][ni][rg] + bv[ni];
                    out[(size_t)rr * NOUT + cg] = v > 0.f ? v : 0.f;
                }
            }
        }
    }
}

// ---------- kernel 4 (fallback): previous m97-structure GEMM (verified 194 us) ----------
__global__ __launch_bounds__(512, 4)
void gemm2(const u16* __restrict__ X, const u16* __restrict__ w2,
           const float* __restrict__ bias, float* __restrict__ out) {
    __shared__ u16 At[BM * 64];     // 16 KB, XOR-swizzled 16B blocks
    __shared__ u16 Bt[BN * 64];     // 32 KB, XOR-swizzled

    const int tid  = threadIdx.x;
    const int lane = tid & 63, wave = tid >> 6;
    const int l15  = lane & 15, q = lane >> 4;
    const int wm   = wave >> 2, wn = wave & 3;

    const int id = blockIdx.x;
    const int p  = (id & 7) + 8 * (id >> 4);
    const int by = (id >> 3) & 1;
    if (p >= 391) return;
    const int row0 = p * BM, col0 = by * BN;

    u32 aoff[2];
    #pragma unroll
    for (int h = 0; h < 2; ++h) {
        int slot = wave * 128 + h * 64 + lane;
        int arow = slot >> 3, ablk = (slot & 7) ^ (arow & 7);
        int grow = row0 + arow; if (grow > N_V - 1) grow = N_V - 1;
        aoff[h] = (u32)grow * (u32)KTOT + (u32)(ablk * 8);
    }
    u32 boff[4];
    #pragma unroll
    for (int i = 0; i < 4; ++i) {
        int slot = wave * 256 + i * 64 + lane;
        int brow = slot >> 3, bblk = (slot & 7) ^ (brow & 7);
        boff[i] = (u32)(col0 + brow) * (u32)KTOT + (u32)(bblk * 8);
    }

    const int eq = l15 & 7;
    const u32 a_rd0 = (u32)(wm * 64 + l15) * 128 + (u32)((q ^ eq) * 16);
    const u32 b_rd0 = (u32)(wn * 64 + l15) * 128 + (u32)((q ^ eq) * 16);

    v4f acc[4][4];
    #pragma unroll
    for (int mi = 0; mi < 4; ++mi)
        #pragma unroll
        for (int ni = 0; ni < 4; ++ni)
            acc[mi][ni] = (v4f){0.f, 0.f, 0.f, 0.f};

    #pragma unroll 1
    for (int kb = 0; kb < NKB; ++kb) {
        __syncthreads();
        #pragma unroll
        for (int h = 0; h < 2; ++h)
            gl2lds(X + aoff[h] + kb * 64, &At[wave * 1024 + h * 512]);
        #pragma unroll
        for (int i = 0; i < 4; ++i)
            gl2lds(w2 + boff[i] + kb * 64, &Bt[wave * 2048 + i * 512]);
        __syncthreads();

        const char* atp = (const char*)At;
        const char* btp = (const char*)Bt;
        #pragma unroll
        for (int s = 0; s < 2; ++s) {
            u32 ao = a_rd0 ^ (u32)(s * 64), bo = b_rd0 ^ (u32)(s * 64);
            v8s a_f[4], b_f[4];
            #pragma unroll
            for (int mi = 0; mi < 4; ++mi) a_f[mi] = *(const v8s*)(atp + ao + mi * 2048);
            #pragma unroll
            for (int ni = 0; ni < 4; ++ni) b_f[ni] = *(const v8s*)(btp + bo + ni * 2048);
            #pragma unroll
            for (int mi = 0; mi < 4; ++mi)
                #pragma unroll
                for (int ni = 0; ni < 4; ++ni)
                    acc[mi][ni] = __builtin_amdgcn_mfma_f32_16x16x32_bf16(
                        a_f[mi], b_f[ni], acc[mi][ni], 0, 0, 0);
        }
    }

    float bv[4];
    #pragma unroll
    for (int ni = 0; ni < 4; ++ni) bv[ni] = bias[ni * 16 + l15];
    #pragma unroll
    for (int mi = 0; mi < 4; ++mi) {
        int rbase = row0 + wm * 64 + mi * 16 + q * 4;
        #pragma unroll
        for (int ni = 0; ni < 4; ++ni) {
            int cg = col0 + wn * 64 + ni * 16 + l15;
            #pragma unroll
            for (int rg = 0; rg < 4; ++rg) {
                int rr = rbase + rg;
                if (rr < N_V) {
                    float v = acc[mi][ni][rg] + bv[ni];
                    out[(size_t)rr * NOUT + cg] = v > 0.f ? v : 0.f;
                }
            }
        }
    }
}

// ================= fallback: R3 fused kernel (used only if ws too small) =================
__global__ __launch_bounds__(512, 2)
void gemm_fused(const float* __restrict__ bary, const u16* __restrict__ msb,
                const u16* __restrict__ w2, const float* __restrict__ bias,
                float* __restrict__ out) {
    __shared__ u16 At[BM * 64];
    __shared__ u16 Bt[2 * BN * 64];

    const int tid  = threadIdx.x;
    const int lane = tid & 63, wave = tid >> 6;
    const int l15  = lane & 15, q = lane >> 4;
    const int wm   = wave >> 2, wn = wave & 3;

    const int id  = blockIdx.x;
    const int bx  = id % 391, by = id / 391;
    const int row0 = bx * BM, col0 = by * BN;

    const int ar  = tid >> 2;
    const u32 acb = (u32)(tid & 3) * 32;
    int an = row0 + ar; if (an > N_V - 1) an = N_V - 1;
    const u32* brow = (const u32*)bary + (size_t)an * 240;
    const u32 an_off = (u32)an * 128 + acb;

    const int e_a = ar & 7;
    const u32 at_w0 = (u32)ar * 128 + (u32)(((2 * (tid & 3)) ^ e_a) * 16);
    const u32 at_w1 = at_w0 ^ 16;

    const int eq = l15 & 7;
    const u32 a_rd0 = (u32)(wm * 64 + l15) * 128 + (u32)((q ^ eq) * 16);
    const u32 b_rd0 = (u32)(wn * 64 + l15) * 128 + (u32)((q ^ eq) * 16);

    const int rl = lane >> 3;
    const int bl = (lane & 7) ^ rl;

    v4f acc[4][4];
    #pragma unroll
    for (int mi = 0; mi < 4; ++mi)
        #pragma unroll
        for (int ni = 0; ni < 4; ++ni)
            acc[mi][ni] = (v4f){0.f, 0.f, 0.f, 0.f};

    v4u G0_0a, G0_0b, G0_1a, G0_1b, G0_2a, G0_2b;
    v4u G1_0a, G1_0b, G1_1a, G1_1b, G1_2a, G1_2b;
    v4u B0lo, B0hi, B1lo, B1hi;
    float w00, w01, w02, w10, w11, w12;
    v4u cv0, cv1;

#define BARY_LOAD(DLO, DHI, kc) do { \
    u32 _d0 = ((u32)((kc) * 6)) & ~3u; \
    DLO = *(const v4u*)(brow + _d0); \
    DHI = *(const v4u*)(brow + _d0 + 4); } while (0)

#define DECODE_ISSUE(PAR, BLO, BHI, Ga0, Gb0, Ga1, Gb1, Ga2, Gb2, W0, W1, W2) do { \
    u32 uf0, uw0, uf1, uw1, uf2, uw2; \
    if (PAR) { uf0 = BLO[2]; uw0 = BLO[3]; uf1 = BHI[0]; uw1 = BHI[1]; uf2 = BHI[2]; uw2 = BHI[3]; } \
    else     { uf0 = BLO[0]; uw0 = BLO[1]; uf1 = BLO[2]; uw1 = BLO[3]; uf2 = BHI[0]; uw2 = BHI[1]; } \
    u32 _o0 = ((u32)(int)__uint_as_float(uf0) << 7) + acb; \
    u32 _o1 = ((u32)(int)__uint_as_float(uf1) << 7) + acb; \
    u32 _o2 = ((u32)(int)__uint_as_float(uf2) << 7) + acb; \
    const char* _mb = (const char*)msb; \
    Ga0 = *(const v4u*)(_mb + _o0); Gb0 = *(const v4u*)(_mb + _o0 + 16); \
    Ga1 = *(const v4u*)(_mb + _o1); Gb1 = *(const v4u*)(_mb + _o1 + 16); \
    Ga2 = *(const v4u*)(_mb + _o2); Gb2 = *(const v4u*)(_mb + _o2 + 16); \
    W0 = __uint_as_float(uw0); W1 = __uint_as_float(uw1); W2 = __uint_as_float(uw2); } while (0)

#define CONVERT(Ga0, Gb0, Ga1, Gb1, Ga2, Gb2, W0, W1, W2) do { \
    _Pragma("unroll") \
    for (int _j = 0; _j < 4; ++_j) { \
        cv0[_j] = ipair(Ga0[_j], Ga1[_j], Ga2[_j], W0, W1, W2); \
        cv1[_j] = ipair(Gb0[_j], Gb1[_j], Gb2[_j], W0, W1, W2); } } while (0)

#define BLDS(KB_LD, BUF) do { \
    _Pragma("unroll") \
    for (int _ii = 0; _ii < 4; ++_ii) { \
        int _we = wave * 4 + _ii; \
        u32 _src = (u32)(col0 + _we * 8 + rl) * KTOT + (u32)(KB_LD) * 64 + (u32)(bl * 8); \
        gl2lds(w2 + _src, &Bt[(BUF) * (BN * 64) + _we * 512]); } } while (0)

#define AT_STORE() do { \
    *(v4u*)((char*)At + at_w0) = cv0; \
    *(v4u*)((char*)At + at_w1) = cv1; } while (0)

#define MFMA_STEP(BUF) do { \
    const char* _atp = (const char*)At; \
    const char* _btp = (const char*)Bt + (BUF) * (BN * 64 * 2); \
    _Pragma("unroll") \
    for (int _s = 0; _s < 2; ++_s) { \
        u32 _ao = a_rd0 ^ (u32)(_s * 64), _bo = b_rd0 ^ (u32)(_s * 64); \
        v8s _af[4], _bf[4]; \
        _Pragma("unroll") \
        for (int _mi = 0; _mi < 4; ++_mi) _af[_mi] = *(const v8s*)(_atp + _ao + _mi * 2048); \
        _Pragma("unroll") \
        for (int _ni = 0; _ni < 4; ++_ni) _bf[_ni] = *(const v8s*)(_btp + _bo + _ni * 2048); \
        _Pragma("unroll") \
        for (int _mi = 0; _mi < 4; ++_mi) \
            _Pragma("unroll") \
            for (int _ni = 0; _ni < 4; ++_ni) \
                acc[_mi][_ni] = __builtin_amdgcn_mfma_f32_16x16x32_bf16( \
                    _af[_mi], _bf[_ni], acc[_mi][_ni], 0, 0, 0); } } while (0)

#define BAR2_12() asm volatile("s_waitcnt vmcnt(12) lgkmcnt(0)\ns_barrier" ::: "memory")
#define BAR2_10() asm volatile("s_waitcnt vmcnt(10) lgkmcnt(0)\ns_barrier" ::: "memory")
#define BAR2_6()  asm volatile("s_waitcnt vmcnt(6) lgkmcnt(0)\ns_barrier"  ::: "memory")
#define BAR2_4()  asm volatile("s_waitcnt vmcnt(4) lgkmcnt(0)\ns_barrier"  ::: "memory")
#define BAR2_0()  asm volatile("s_waitcnt vmcnt(0) lgkmcnt(0)\ns_barrier"  ::: "memory")
#define BAR1()    asm volatile("s_barrier" ::: "memory")

    BARY_LOAD(B0lo, B0hi, 0);
    DECODE_ISSUE(0, B0lo, B0hi, G0_0a, G0_0b, G0_1a, G0_1b, G0_2a, G0_2b, w00, w01, w02);
    BARY_LOAD(B1lo, B1hi, 1);
    DECODE_ISSUE(1, B1lo, B1hi, G1_0a, G1_0b, G1_1a, G1_1b, G1_2a, G1_2b, w10, w11, w12);
    BARY_LOAD(B0lo, B0hi, 2);
    BLDS(0, 0);

    #pragma unroll 1
    for (int i = 0; i < 20; ++i) {
        {
            const int kb = 2 * i;
            CONVERT(G0_0a, G0_0b, G0_1a, G0_1b, G0_2a, G0_2b, w00, w01, w02);
            if (kb <= 36) BARY_LOAD(B1lo, B1hi, kb + 3);
            if (kb <= 37) {
                DECODE_ISSUE(0, B0lo, B0hi, G0_0a, G0_0b, G0_1a, G0_1b, G0_2a, G0_2b,
                             w00, w01, w02);
            } else if (kb == 38) {
                G0_0a = *(const v4u*)((const char*)msb + an_off);
                G0_0b = *(const v4u*)((const char*)msb + an_off + 16);
            }
            BAR1();
            BLDS(kb + 1, 1);
            AT_STORE();
            if (kb <= 36) BAR2_12(); else BAR2_6();
            MFMA_STEP(0);
        }
        {
            const int kb = 2 * i + 1;
            CONVERT(G1_0a, G1_0b, G1_1a, G1_1b, G1_2a, G1_2b, w10, w11, w12);
            if (kb <= 36) BARY_LOAD(B0lo, B0hi, kb + 3);
            if (kb <= 37)
                DECODE_ISSUE(1, B1lo, B1hi, G1_0a, G1_0b, G1_1a, G1_1b, G1_2a, G1_2b,
                             w10, w11, w12);
            BAR1();
            BLDS(kb + 1, 0);
            AT_STORE();
            if (kb <= 36) BAR2_12();
            else if (kb == 37) BAR2_10();
            else BAR2_4();
            MFMA_STEP(1);
        }
    }
    {
        cv0 = G0_0a; cv1 = G0_0b;
        BAR1();
        AT_STORE();
        BAR2_0();
        MFMA_STEP(0);
    }

    float bv[4];
    #pragma unroll
    for (int ni = 0; ni < 4; ++ni) bv[ni] = bias[ni * 16 + l15];
    #pragma unroll
    for (int mi = 0; mi < 4; ++mi) {
        int rbase = row0 + wm * 64 + mi * 16 + q * 4;
        #pragma unroll
        for (int ni = 0; ni < 4; ++ni) {
            int cg = col0 + wn * 64 + ni * 16 + l15;
            #pragma unroll
            for (int rg = 0; rg < 4; ++rg) {
                int rr = rbase + rg;
                if (rr < N_V) {
                    float v = acc[mi][ni][rg] + bv[ni];
                    out[(size_t)rr * NOUT + cg] = v > 0.f ? v : 0.f;
                }
            }
        }
    }
}

extern "C" void kernel_launch(void* const* d_in, const int* in_sizes, int n_in,
                              void* d_out, int out_size, void* d_ws, size_t ws_size,
                              hipStream_t stream) {
    const float* ms    = (const float*)d_in[0];
    const float* bary  = (const float*)d_in[1];
    const float* nw    = (const float*)d_in[2];
    const float* cw    = (const float*)d_in[3];
    const float* bias  = (const float*)d_in[4];
    const float* coeff = (const float*)d_in[5];
    float* out = (float*)d_out;

    u16* msb = (u16*)d_ws;                        // 6,400,000 B
    u16* w2  = (u16*)((char*)d_ws + 6400000);     // 2,686,976 B
    const size_t x_off  = 9087104;                // 128-aligned
    const size_t x_need = x_off + (size_t)N_V * KTOT * 2;   // + 262,400,000 B
    u16* X = (u16*)((char*)d_ws + x_off);

    if (ws_size >= x_need) {
        static int dyn_ok = -1;
        if (dyn_ok < 0) {
            dyn_ok = (hipFuncSetAttribute((const void*)gemm5,
                          hipFuncAttributeMaxDynamicSharedMemorySize,
                          98304) == hipSuccess) ? 1 : 0;
        }
        cast_ms<<<3125, 256, 0, stream>>>(ms, msb, X);
        build_w2<<<(NOUT * KTOT + 255) / 256, 256, 0, stream>>>(nw, cw, coeff, w2);
        build_x<<<31250, 256, 0, stream>>>(bary, msb, X);
        if (dyn_ok)
            gemm5<<<400, 512, 98304, stream>>>(X, w2, bias, out);
        else
            gemm2<<<784, 512, 0, stream>>>(X, w2, bias, out);
    } else {
        cast_ms<<<3125, 256, 0, stream>>>(ms, msb, (u16*)nullptr);
        build_w2<<<(NOUT * KTOT + 255) / 256, 256, 0, stream>>>(nw, cw, coeff, w2);
        gemm_fused<<<782, 512, 0, stream>>>(bary, msb, w2, bias, out);
    }
}